// Round 4
// baseline (143.492 us; speedup 1.0000x reference)
//
#include <hip/hip_runtime.h>
#include <math.h>

#define BLOCK 512        // 8 waves/block; 4 blocks/CU = 32 waves = 100% occupancy
#define GOAL_MAX 256     // stage goals in LDS (12*H words) when H <= GOAL_MAX

typedef unsigned int u32;

__global__ __launch_bounds__(BLOCK, 8) void traj_cost_kernel(
    const float* __restrict__ pos,    // (N, 3)
    const float* __restrict__ rot,    // (N, 3, 3)
    const float* __restrict__ gpos,   // (H, 3)
    const float* __restrict__ grot,   // (H, 3, 3)
    float* __restrict__ out,          // cost[N] | rot_err_norm[N] | goal_dist[N]
    long long N, int H, int hstaged)
{
  // Dynamic LDS: [s_rot 9*BLOCK][s_pos 3*BLOCK][sg 12*H (SoA) if staged]
  // 24KB + 12KB(H=256) = 36.9KB -> exactly 4 blocks/CU, wave-limited (100%).
  extern __shared__ float smem[];
  float* s_rot = smem;                  // 9*BLOCK
  float* s_pos = smem + 9 * BLOCK;      // 3*BLOCK
  float* sg    = smem + 12 * BLOCK;     // 12*H, SoA: sg[c*H + h]

  const int tid = threadIdx.x;
  const long long base = (long long)blockIdx.x * BLOCK;

  // ---- pose staging: fully coalesced float4 ----
  if (base + BLOCK <= N) {
    // rot chunk = 512*9 floats = 1152 float4; pos chunk = 384 float4.
    // Block base byte offsets (18432 / 6144) are 16B-aligned.
    const float4* r4 = (const float4*)(rot + base * 9);
    float4* s4 = (float4*)s_rot;
    s4[tid]        = r4[tid];
    s4[tid + 512]  = r4[tid + 512];
    if (tid < 128) s4[tid + 1024] = r4[tid + 1024];
    const float4* p4 = (const float4*)(pos + base * 3);
    float4* sp4 = (float4*)s_pos;
    if (tid < 384) sp4[tid] = p4[tid];
  } else {
    const u32 nel = (u32)(N - base);
    for (u32 k = tid; k < nel * 9u; k += BLOCK) s_rot[k] = rot[base * 9 + k];
    for (u32 k = tid; k < nel * 3u; k += BLOCK) s_pos[k] = pos[base * 3 + k];
  }

  // ---- goal staging: SoA transpose, coalesced global reads, once per block.
  // Compute-phase reads sg[c*H + h] are lane-stride-1 -> conflict-free.
  if (hstaged) {
    const u32 uH = (u32)H;
    for (u32 k = tid; k < 9u * uH; k += BLOCK) sg[(k % 9u) * uH + k / 9u] = grot[k];
    for (u32 k = tid; k < 3u * uH; k += BLOCK) sg[(9u + k % 3u) * uH + k / 3u] = gpos[k];
  }
  __syncthreads();

  const long long idx = base + tid;
  if (idx >= N) return;

  const u32 h0 = (u32)(base % (long long)H);     // one 64-bit mod, block-uniform
  const u32 h  = (h0 + (u32)tid) % (u32)H;       // 32-bit

  float R[9], P[3], G[9], GP[3];
  // pose reads: lane word-stride 9 / 3, gcd(9,32)=gcd(3,32)=1 -> free 2-way
  #pragma unroll
  for (int c = 0; c < 9; ++c) R[c] = s_rot[tid * 9 + c];
  #pragma unroll
  for (int c = 0; c < 3; ++c) P[c] = s_pos[tid * 3 + c];
  if (hstaged) {
    #pragma unroll
    for (int c = 0; c < 9; ++c) G[c] = sg[c * H + (int)h];
    #pragma unroll
    for (int c = 0; c < 3; ++c) GP[c] = sg[(9 + c) * H + (int)h];
  } else {
    #pragma unroll
    for (int c = 0; c < 9; ++c) G[c] = grot[(size_t)h * 9 + c];
    #pragma unroll
    for (int c = 0; c < 3; ++c) GP[c] = gpos[(size_t)h * 3 + c];
  }

  // t[i] = ee_t_g[i] = -sum_j G[j,i]*GP[j] + sum_j R[j,i]*P[j]
  float t[3];
  #pragma unroll
  for (int i = 0; i < 3; ++i) {
    float a = 0.f;
    #pragma unroll
    for (int j = 0; j < 3; ++j)
      a += R[j * 3 + i] * P[j] - G[j * 3 + i] * GP[j];
    t[i] = a;
  }
  const float pos_err = t[0] * t[0] + t[1] * t[1] + t[2] * t[2];
  const float goal_dist = __builtin_amdgcn_sqrtf(pos_err);   // arg >= 0

  // ee_R_g[i,j] = sum_k G[k,i]*R[k,j]; d = I - ee_R_g
  float rn[3];
  #pragma unroll
  for (int i = 0; i < 3; ++i) {
    float q = 0.f;
    #pragma unroll
    for (int j = 0; j < 3; ++j) {
      float m = G[0 * 3 + i] * R[0 * 3 + j]
              + G[1 * 3 + i] * R[1 * 3 + j]
              + G[2 * 3 + i] * R[2 * 3 + j];
      float d = (i == j ? 1.f : 0.f) - m;
      q += d * d;
    }
    rn[i] = __builtin_amdgcn_sqrtf(q);                       // arg >= 0
  }
  const float ssum = rn[0] + rn[1] + rn[2];
  const float q2 = rn[0] * rn[0] + rn[1] * rn[1] + rn[2] * rn[2];
  const float rot_err_norm = __builtin_amdgcn_sqrtf(q2);

  // rot_err = ssum^2 hinged on goal_dist <= 100; convergence thresholds are 0
  // (no-op on non-negative values); sqrt(ssum^2) == ssum since ssum >= 0.
  const float cost = (goal_dist <= 100.0f ? ssum : 0.f) + goal_dist;

  out[idx]         = cost;
  out[N + idx]     = rot_err_norm;
  out[2 * N + idx] = goal_dist;
}

extern "C" void kernel_launch(void* const* d_in, const int* in_sizes, int n_in,
                              void* d_out, int out_size, void* d_ws, size_t ws_size,
                              hipStream_t stream) {
  const float* pos  = (const float*)d_in[0];
  const float* rot  = (const float*)d_in[1];
  const float* gpos = (const float*)d_in[2];
  const float* grot = (const float*)d_in[3];
  float* out = (float*)d_out;

  const long long N = (long long)in_sizes[0] / 3;   // B*H poses
  const int H = in_sizes[2] / 3;

  const int blocks = (int)((N + BLOCK - 1) / BLOCK);
  // Stage goals only if the combined request stays well under the LDS cap.
  const int hstaged = (H <= GOAL_MAX &&
                       (12 * BLOCK + 12 * H) * sizeof(float) <= 64 * 1024) ? 1 : 0;
  const size_t smem = (size_t)(12 * BLOCK + (hstaged ? 12 * H : 0)) * sizeof(float);

  traj_cost_kernel<<<blocks, BLOCK, smem, stream>>>(pos, rot, gpos, grot, out,
                                                    N, H, hstaged);
}